// Round 2
// baseline (326.177 us; speedup 1.0000x reference)
//
#include <hip/hip_runtime.h>

// TinyDLRM: out[i] = sigmoid( relu( f @ w1 + b1 ) @ w2 + b2 )
// f = [user_emb(8) | item_emb(8) | cat_emb(8) | dense(2)]  (26 floats)
//
// v3 theory: v1/v2 both sit at ~3.4 TB/s on the L2-miss path (537 MB fetch,
// ~8.4M random 64B lines from the 64MB user/item tables -> irreducible).
// Question: queue/concurrency ceiling or fabric ceiling?
//   outstanding-reqs math: ~64 req/CU x 64B / ~290ns x 256 CU ~= 3.6 TB/s,
//   i.e. measured rate == latency-under-load x queue depth. So v3 maximizes
//   true concurrency STRUCTURALLY:
//   - persistent grid-stride loop (2048 blocks = 8/CU = 32 waves/CU max occ,
//     no launch/tail churn; batch/stride = exactly 8 iters/thread)
//   - software pipeline: iteration n prefetches ids(n+1) while gathers(n)
//     are in flight -> per-iteration serial chain is ONE memory round-trip
//     (gather) instead of two (id -> gather)
//   - gathers + dense issued back-to-back; compiler waits vmcnt(3) for
//     gathers while the 3 next-ids stay outstanding (in-order vmcnt)
//   - float2 packed MLP -> v_pk_fma_f32 halves VALU issue (208 pk-FMAs vs
//     416 scalar), removing VALU as a co-bottleneck
// Weights stay wave-uniform global reads -> SGPRs.
// Decision rule: if dur is unchanged at >=85% occupancy and <=45% VALUBusy,
// the ~3.5 TB/s random-64B fetch path is the roofline.

#define HIDDEN 16
#define IN_DIM 26
#define BLOCK  256
#define GRID   2048

typedef float v4f __attribute__((ext_vector_type(4)));
typedef float v2f __attribute__((ext_vector_type(2)));

__device__ __forceinline__ float sigmoid_mlp(
    v4f u0, v4f u1, v4f p0, v4f p1, v4f c0, v4f c1, v2f dd,
    const v2f* __restrict__ w1v,  // [26*8] float2 pairs of w1 rows
    const v2f* __restrict__ b1v,  // [8]
    const float* __restrict__ w2, // [16]
    const float* __restrict__ b2) // [1]
{
    float f[IN_DIM] = {
        u0.x, u0.y, u0.z, u0.w, u1.x, u1.y, u1.z, u1.w,
        p0.x, p0.y, p0.z, p0.w, p1.x, p1.y, p1.z, p1.w,
        c0.x, c0.y, c0.z, c0.w, c1.x, c1.y, c1.z, c1.w,
        dd.x, dd.y
    };

    // h as 8 float2 lanes -> v_pk_fma_f32 (2 fp32 FMAs / instr)
    v2f h[HIDDEN / 2];
#pragma unroll
    for (int j = 0; j < HIDDEN / 2; ++j) h[j] = b1v[j];

#pragma unroll
    for (int k = 0; k < IN_DIM; ++k) {
        v2f fk = { f[k], f[k] };
#pragma unroll
        for (int j = 0; j < HIDDEN / 2; ++j) {
            h[j] = fk * w1v[k * (HIDDEN / 2) + j] + h[j];  // contracts to pk_fma
        }
    }

    float acc = b2[0];
#pragma unroll
    for (int j = 0; j < HIDDEN / 2; ++j) {
        acc = fmaf(fmaxf(h[j].x, 0.0f), w2[2 * j],     acc);
        acc = fmaf(fmaxf(h[j].y, 0.0f), w2[2 * j + 1], acc);
    }
    return 1.0f / (1.0f + __expf(-acc));
}

__global__ __launch_bounds__(BLOCK, 8) void tiny_dlrm_kernel(
    const int*   __restrict__ user_id,
    const int*   __restrict__ item_id,
    const int*   __restrict__ cat_id,
    const float* __restrict__ dense,      // [B,2]
    const float* __restrict__ user_table, // [NU,8]
    const float* __restrict__ item_table, // [NI,8]
    const float* __restrict__ cat_table,  // [NC,8]
    const float* __restrict__ w1,         // [26,16] row-major
    const float* __restrict__ b1,         // [16]
    const float* __restrict__ w2,         // [16]
    const float* __restrict__ b2,         // [1]
    float*       __restrict__ out,        // [B]
    int batch)
{
    const int stride = gridDim.x * BLOCK;
    int i = blockIdx.x * BLOCK + threadIdx.x;
    if (i >= batch) return;

    const v2f* w1v = (const v2f*)w1;
    const v2f* b1v = (const v2f*)b1;

    // prologue: ids for the first iteration
    int u = __builtin_nontemporal_load(user_id + i);
    int v = __builtin_nontemporal_load(item_id + i);
    int c = __builtin_nontemporal_load(cat_id  + i);

    for (;;) {
        // --- issue this iteration's gathers (ids already resident) ---
        const v4f* up = (const v4f*)(user_table + ((size_t)(unsigned)u << 3));
        const v4f* ip = (const v4f*)(item_table + ((size_t)(unsigned)v << 3));
        const v4f* cp = (const v4f*)(cat_table  + ((size_t)(unsigned)c << 3));
        v4f u0 = up[0], u1 = up[1];
        v4f p0 = ip[0], p1 = ip[1];
        v4f c0 = cp[0], c1 = cp[1];
        v2f dd = __builtin_nontemporal_load((const v2f*)dense + i);

        // --- prefetch next iteration's ids (stay outstanding across compute) ---
        int inext = i + stride;
        bool more = inext < batch;
        int un = 0, vn = 0, cn = 0;
        if (more) {
            un = __builtin_nontemporal_load(user_id + inext);
            vn = __builtin_nontemporal_load(item_id + inext);
            cn = __builtin_nontemporal_load(cat_id  + inext);
        }

        // --- compute (waits vmcnt(3): gathers+dense done, next-ids in flight) ---
        float o = sigmoid_mlp(u0, u1, p0, p1, c0, c1, dd, w1v, b1v, w2, b2);
        __builtin_nontemporal_store(o, out + i);

        if (!more) break;
        i = inext; u = un; v = vn; c = cn;
    }
}

extern "C" void kernel_launch(void* const* d_in, const int* in_sizes, int n_in,
                              void* d_out, int out_size, void* d_ws, size_t ws_size,
                              hipStream_t stream) {
    const int*   user_id    = (const int*)d_in[0];
    const int*   item_id    = (const int*)d_in[1];
    const int*   cat_id     = (const int*)d_in[2];
    const float* dense      = (const float*)d_in[3];
    const float* user_table = (const float*)d_in[4];
    const float* item_table = (const float*)d_in[5];
    const float* cat_table  = (const float*)d_in[6];
    const float* w1         = (const float*)d_in[7];
    const float* b1         = (const float*)d_in[8];
    const float* w2         = (const float*)d_in[9];
    const float* b2         = (const float*)d_in[10];
    float* out = (float*)d_out;

    int batch = in_sizes[0];
    int nblocks = (batch + BLOCK - 1) / BLOCK;
    int grid = nblocks < GRID ? nblocks : GRID;
    tiny_dlrm_kernel<<<grid, BLOCK, 0, stream>>>(
        user_id, item_id, cat_id, dense,
        user_table, item_table, cat_table,
        w1, b1, w2, b2, out, batch);
}

// Round 3
// 292.909 us; speedup vs baseline: 1.1136x; 1.1136x over previous
//
#include <hip/hip_runtime.h>

// TinyDLRM: out[i] = sigmoid( relu( f @ w1 + b1 ) @ w2 + b2 )
// f = [user_emb(8) | item_emb(8) | cat_emb(8) | dense(2)]  (26 floats)
//
// v4 = best-known structure (v1) + packed-FMA MLP. Evidence from v1/v2/v3:
//   - hbm_gbps is PINNED at 3.43-3.47 TB/s across three different structures
//     (sunk gathers/24 VGPR, batched/28, pipelined grid-stride/32) -> the
//     random-64B gather service rate is the limiter, not latency hiding.
//   - v1's FETCH (537 MB) is already the byte floor: 100 MB streams +
//     8.39M user/item gathers x 64B line (cat table is L2-resident).
//   - Therefore: minimize bytes (no nt hints -- v2 showed they don't cut
//     fetch; v3's prefetch+tight regs ADDED 98 MB via rematerialization and
//     scratch), keep the compiler's register-frugal schedule (1 sample/
//     thread, no forced hoisting), and halve VALU issue with v_pk_fma_f32
//     so compute stays far off the critical path.

#define HIDDEN 16
#define IN_DIM 26

typedef float v4f __attribute__((ext_vector_type(4)));
typedef float v2f __attribute__((ext_vector_type(2)));

__global__ __launch_bounds__(256) void tiny_dlrm_kernel(
    const int*   __restrict__ user_id,
    const int*   __restrict__ item_id,
    const int*   __restrict__ cat_id,
    const float* __restrict__ dense,      // [B,2]
    const float* __restrict__ user_table, // [NU,8]
    const float* __restrict__ item_table, // [NI,8]
    const float* __restrict__ cat_table,  // [NC,8]
    const float* __restrict__ w1,         // [26,16] row-major
    const float* __restrict__ b1,         // [16]
    const float* __restrict__ w2,         // [16]
    const float* __restrict__ b2,         // [1]
    float*       __restrict__ out,        // [B]
    int batch)
{
    int i = blockIdx.x * blockDim.x + threadIdx.x;
    if (i >= batch) return;

    // --- gather (schedule left to the compiler: memory path is rate-limited,
    //     so the register-frugal sunk-gather schedule is the right one) ---
    int u = user_id[i];
    int v = item_id[i];
    int c = cat_id[i];

    const v4f* up = (const v4f*)(user_table + ((size_t)(unsigned)u << 3));
    const v4f* ip = (const v4f*)(item_table + ((size_t)(unsigned)v << 3));
    const v4f* cp = (const v4f*)(cat_table  + ((size_t)(unsigned)c << 3));
    v4f u0 = up[0], u1 = up[1];
    v4f i0 = ip[0], i1 = ip[1];
    v4f c0 = cp[0], c1 = cp[1];
    v2f dd = ((const v2f*)dense)[i];

    float f[IN_DIM] = {
        u0.x, u0.y, u0.z, u0.w, u1.x, u1.y, u1.z, u1.w,
        i0.x, i0.y, i0.z, i0.w, i1.x, i1.y, i1.z, i1.w,
        c0.x, c0.y, c0.z, c0.w, c1.x, c1.y, c1.z, c1.w,
        dd.x, dd.y
    };

    // --- layer 1 as 8 float2 lanes -> v_pk_fma_f32 (w1 reads wave-uniform
    //     -> s_load + pk_fma with SGPR-pair operand) ---
    const v2f* w1v = (const v2f*)w1;
    const v2f* b1v = (const v2f*)b1;

    v2f h[HIDDEN / 2];
#pragma unroll
    for (int j = 0; j < HIDDEN / 2; ++j) h[j] = b1v[j];

#pragma unroll
    for (int k = 0; k < IN_DIM; ++k) {
        v2f fk = { f[k], f[k] };
#pragma unroll
        for (int j = 0; j < HIDDEN / 2; ++j) {
            h[j] = fk * w1v[k * (HIDDEN / 2) + j] + h[j];  // contracts to pk_fma
        }
    }

    // --- layer 2 + sigmoid ---
    float acc = b2[0];
#pragma unroll
    for (int j = 0; j < HIDDEN / 2; ++j) {
        acc = fmaf(fmaxf(h[j].x, 0.0f), w2[2 * j],     acc);
        acc = fmaf(fmaxf(h[j].y, 0.0f), w2[2 * j + 1], acc);
    }

    out[i] = 1.0f / (1.0f + __expf(-acc));
}

extern "C" void kernel_launch(void* const* d_in, const int* in_sizes, int n_in,
                              void* d_out, int out_size, void* d_ws, size_t ws_size,
                              hipStream_t stream) {
    const int*   user_id    = (const int*)d_in[0];
    const int*   item_id    = (const int*)d_in[1];
    const int*   cat_id     = (const int*)d_in[2];
    const float* dense      = (const float*)d_in[3];
    const float* user_table = (const float*)d_in[4];
    const float* item_table = (const float*)d_in[5];
    const float* cat_table  = (const float*)d_in[6];
    const float* w1         = (const float*)d_in[7];
    const float* b1         = (const float*)d_in[8];
    const float* w2         = (const float*)d_in[9];
    const float* b2         = (const float*)d_in[10];
    float* out = (float*)d_out;

    int batch = in_sizes[0];
    int block = 256;
    int grid = (batch + block - 1) / block;
    tiny_dlrm_kernel<<<grid, block, 0, stream>>>(
        user_id, item_id, cat_id, dense,
        user_table, item_table, cat_table,
        w1, b1, w2, b2, out, batch);
}

// Round 4
// 289.912 us; speedup vs baseline: 1.1251x; 1.0103x over previous
//
#include <hip/hip_runtime.h>

// TinyDLRM: out[i] = sigmoid( relu( f @ w1 + b1 ) @ w2 + b2 )
// f = [user_emb(8) | item_emb(8) | cat_emb(8) | dense(2)]  (26 floats)
//
// FINAL (v5 == v1, the best-measured variant). Roofline evidence from the
// session (v1-v4, rocprof on gfx950):
//   - FETCH_SIZE pinned at ~540 MB = byte floor: 84 MB compulsory streams
//     (ids+dense) + ~8.4M random 64B-line gathers into the 64 MB user/item
//     tables (- ~13% incidental L2 hits); cat table (320 KB) is L2-resident.
//     WRITE_SIZE 16.4 MB = exact output floor.
//   - hbm_gbps pinned at 3.43 +/- 0.05 TB/s across FOUR structures:
//     v1 sunk-gathers/24 VGPR/VALU 32%, v2 batched/28, v3 pipelined
//     grid-stride/32, v4 packed-FMA/20/VALU 19%. Raising software
//     concurrency (v2, v3) did not move the rate -> per-CU outstanding-line
//     cap (~60 lines/CU by Little's law at ~290 ns) x latency is the
//     hardware service ceiling for random 64B gathers.
//   - Floor arithmetic: 556 MB / 3.43 TB/s ~= 162 us, which this kernel hits.
//   - Compute is irrelevant: VALUBusy 19-32%, MfmaUtil 0, zero LDS traffic.
// What would have to change for more: id locality (doesn't exist in random
// data) or a table format that fits per-XCD L2 8x-replicated (bf16 halves
// footprint to 32 MB, still 8x too big, and 64B line fetches don't shrink).
//
// Structure notes:
//   - one thread per sample; compiler's register-frugal schedule (VGPR 24)
//     interleaves gathers with FMAs -- optimal when the memory path is
//     rate-limited (forcing hoisted loads was neutral-to-worse).
//   - weights read with wave-uniform indices -> s_load to SGPRs, FMAs take
//     the SGPR operand directly; no LDS staging needed.

#define HIDDEN 16
#define IN_DIM 26

__global__ __launch_bounds__(256) void tiny_dlrm_kernel(
    const int*   __restrict__ user_id,
    const int*   __restrict__ item_id,
    const int*   __restrict__ cat_id,
    const float* __restrict__ dense,      // [B,2]
    const float* __restrict__ user_table, // [NU,8]
    const float* __restrict__ item_table, // [NI,8]
    const float* __restrict__ cat_table,  // [NC,8]
    const float* __restrict__ w1,         // [26,16] row-major
    const float* __restrict__ b1,         // [16]
    const float* __restrict__ w2,         // [16]
    const float* __restrict__ b2,         // [1]
    float*       __restrict__ out,        // [B]
    int batch)
{
    int i = blockIdx.x * blockDim.x + threadIdx.x;
    if (i >= batch) return;

    // --- gather ---
    int u = user_id[i];
    int v = item_id[i];
    int c = cat_id[i];

    const float4* up = (const float4*)(user_table + (size_t)u * 8);
    const float4* ip = (const float4*)(item_table + (size_t)v * 8);
    const float4* cp = (const float4*)(cat_table  + (size_t)c * 8);
    float4 u0 = up[0], u1 = up[1];
    float4 i0 = ip[0], i1 = ip[1];
    float4 c0 = cp[0], c1 = cp[1];
    float2 dd = ((const float2*)dense)[i];

    float f[IN_DIM] = {
        u0.x, u0.y, u0.z, u0.w, u1.x, u1.y, u1.z, u1.w,
        i0.x, i0.y, i0.z, i0.w, i1.x, i1.y, i1.z, i1.w,
        c0.x, c0.y, c0.z, c0.w, c1.x, c1.y, c1.z, c1.w,
        dd.x, dd.y
    };

    // --- layer 1: h = f @ w1 + b1 (w1 accesses are wave-uniform -> SGPRs) ---
    float h[HIDDEN];
#pragma unroll
    for (int j = 0; j < HIDDEN; ++j) h[j] = b1[j];

#pragma unroll
    for (int k = 0; k < IN_DIM; ++k) {
        float fk = f[k];
#pragma unroll
        for (int j = 0; j < HIDDEN; ++j) {
            h[j] = fmaf(fk, w1[k * HIDDEN + j], h[j]);
        }
    }

    // --- layer 2: logits = relu(h) @ w2 + b2; sigmoid ---
    float acc = b2[0];
#pragma unroll
    for (int j = 0; j < HIDDEN; ++j) {
        acc = fmaf(fmaxf(h[j], 0.0f), w2[j], acc);
    }

    out[i] = 1.0f / (1.0f + __expf(-acc));
}

extern "C" void kernel_launch(void* const* d_in, const int* in_sizes, int n_in,
                              void* d_out, int out_size, void* d_ws, size_t ws_size,
                              hipStream_t stream) {
    const int*   user_id    = (const int*)d_in[0];
    const int*   item_id    = (const int*)d_in[1];
    const int*   cat_id     = (const int*)d_in[2];
    const float* dense      = (const float*)d_in[3];
    const float* user_table = (const float*)d_in[4];
    const float* item_table = (const float*)d_in[5];
    const float* cat_table  = (const float*)d_in[6];
    const float* w1         = (const float*)d_in[7];
    const float* b1         = (const float*)d_in[8];
    const float* w2         = (const float*)d_in[9];
    const float* b2         = (const float*)d_in[10];
    float* out = (float*)d_out;

    int batch = in_sizes[0];
    int block = 256;
    int grid = (batch + block - 1) / block;
    tiny_dlrm_kernel<<<grid, block, 0, stream>>>(
        user_id, item_id, cat_id, dense,
        user_table, item_table, cat_table,
        w1, b1, w2, b2, out, batch);
}